// Round 1
// baseline (21382.062 us; speedup 1.0000x reference)
//
#include <hip/hip_runtime.h>
#include <math.h>

#define B_   128
#define NZ_  128
#define H_   512
#define V_   8192
#define S_   64
#define TH_  1536   // 3H
#define H2_  1024   // 2H
#define SOS_ 8191

__device__ __forceinline__ float leaky(float x) { return x > 0.f ? x : 0.2f * x; }
__device__ __forceinline__ float sigm(float x)  { return 1.f / (1.f + expf(-x)); }

// ---------------- Threefry-2x32-20 (exact JAX) ----------------
__device__ __forceinline__ void tfround(unsigned &x0, unsigned &x1, int r) {
  x0 += x1;
  x1 = (x1 << r) | (x1 >> (32 - r));
  x1 ^= x0;
}
__device__ __forceinline__ void threefry(unsigned k0, unsigned k1,
                                         unsigned &x0, unsigned &x1) {
  unsigned ks2 = k0 ^ k1 ^ 0x1BD11BDAu;
  x0 += k0; x1 += k1;
  tfround(x0,x1,13); tfround(x0,x1,15); tfround(x0,x1,26); tfround(x0,x1,6);
  x0 += k1; x1 += ks2 + 1u;
  tfround(x0,x1,17); tfround(x0,x1,29); tfround(x0,x1,16); tfround(x0,x1,24);
  x0 += ks2; x1 += k0 + 2u;
  tfround(x0,x1,13); tfround(x0,x1,15); tfround(x0,x1,26); tfround(x0,x1,6);
  x0 += k0; x1 += k1 + 3u;
  tfround(x0,x1,17); tfround(x0,x1,29); tfround(x0,x1,16); tfround(x0,x1,24);
  x0 += k1; x1 += ks2 + 4u;
  tfround(x0,x1,13); tfround(x0,x1,15); tfround(x0,x1,26); tfround(x0,x1,6);
  x0 += ks2; x1 += k0 + 5u;
}

// ---------------- setup: z0 = BN1(leaky(z@W.T+b)); si_z = BN2(z0 cols) ----
__global__ __launch_bounds__(128) void setup_z0(
    const float* __restrict__ z, const float* __restrict__ w,
    const float* __restrict__ bz,
    const float* __restrict__ g1, const float* __restrict__ b1,
    const float* __restrict__ g2, const float* __restrict__ b2,
    float* __restrict__ hx, float* __restrict__ hm,
    float* __restrict__ si_z, int* __restrict__ prev)
{
  int j = blockIdx.x;      // column 0..511
  int b = threadIdx.x;     // row 0..127
  __shared__ float red[128];
  float acc = bz[j];
  const float* wr = w + j * NZ_;
  const float* zr = z + b * NZ_;
  for (int k = 0; k < NZ_; ++k) acc += zr[k] * wr[k];
  float x = leaky(acc);
  // BN1 (two-pass, batch axis)
  red[b] = x; __syncthreads();
  for (int s = 64; s > 0; s >>= 1) { if (b < s) red[b] += red[b+s]; __syncthreads(); }
  float mu = red[0] * (1.f/128.f); __syncthreads();
  float d = x - mu;
  red[b] = d * d; __syncthreads();
  for (int s = 64; s > 0; s >>= 1) { if (b < s) red[b] += red[b+s]; __syncthreads(); }
  float var = red[0] * (1.f/128.f); __syncthreads();
  float z0 = (g1[j] * d) * (1.f / sqrtf(var + 1e-5f)) + b1[j];
  hx[b*H_ + j] = z0;
  hm[b*H_ + j] = z0;
  // BN2 on z0 column (si column 512+j) -- step-invariant
  red[b] = z0; __syncthreads();
  for (int s = 64; s > 0; s >>= 1) { if (b < s) red[b] += red[b+s]; __syncthreads(); }
  float mu2 = red[0] * (1.f/128.f); __syncthreads();
  float d2 = z0 - mu2;
  red[b] = d2 * d2; __syncthreads();
  for (int s = 64; s > 0; s >>= 1) { if (b < s) red[b] += red[b+s]; __syncthreads(); }
  float var2 = red[0] * (1.f/128.f);
  si_z[b*H_ + j] = (g2[512+j] * d2) * (1.f / sqrtf(var2 + 1e-5f)) + b2[512+j];
  if (j == 0) prev[b] = SOS_;
}

// ---------------- per-step: x_bn = BN2(leaky(emb[prev])) ----------------
__global__ __launch_bounds__(128) void embed_bn(
    const float* __restrict__ emb, const int* __restrict__ prev,
    const float* __restrict__ g2, const float* __restrict__ b2,
    float* __restrict__ x_bn)
{
  int j = blockIdx.x;
  int b = threadIdx.x;
  __shared__ float red[128];
  int p = prev[b];
  float x = leaky(emb[(size_t)p * H_ + j]);
  red[b] = x; __syncthreads();
  for (int s = 64; s > 0; s >>= 1) { if (b < s) red[b] += red[b+s]; __syncthreads(); }
  float mu = red[0] * (1.f/128.f); __syncthreads();
  float d = x - mu;
  red[b] = d * d; __syncthreads();
  for (int s = 64; s > 0; s >>= 1) { if (b < s) red[b] += red[b+s]; __syncthreads(); }
  float var = red[0] * (1.f/128.f);
  x_bn[b*H_ + j] = (g2[j] * d) * (1.f / sqrtf(var + 1e-5f)) + b2[j];
}

// ---------------- generic C = A @ Bt^T (+bias)(+C0) ----------------
#define GBM 64
#define GBN 64
#define GBK 32
__global__ __launch_bounds__(256) void gemm_nt(
    const float* __restrict__ A, int lda,
    const float* __restrict__ Bt, int ldb,
    const float* __restrict__ bias,
    const float* __restrict__ C0,
    float* __restrict__ C, int ldc, int K)
{
  __shared__ float As[GBM][GBK+1];
  __shared__ float Bs[GBN][GBK+1];
  int bm = blockIdx.y * GBM, bn = blockIdx.x * GBN;
  int tid = threadIdx.x;
  int tm = (tid >> 4) << 2, tn = (tid & 15) << 2;
  float acc[4][4] = {};
  for (int k0 = 0; k0 < K; k0 += GBK) {
    for (int i = tid; i < GBM * GBK; i += 256) {
      int r = i >> 5, c = i & 31;
      As[r][c] = A[(size_t)(bm + r) * lda + k0 + c];
      Bs[r][c] = Bt[(size_t)(bn + r) * ldb + k0 + c];
    }
    __syncthreads();
    #pragma unroll
    for (int k = 0; k < GBK; ++k) {
      float av[4], bv[4];
      #pragma unroll
      for (int q = 0; q < 4; ++q) { av[q] = As[tm+q][k]; bv[q] = Bs[tn+q][k]; }
      #pragma unroll
      for (int a = 0; a < 4; ++a)
        #pragma unroll
        for (int c = 0; c < 4; ++c)
          acc[a][c] += av[a] * bv[c];
    }
    __syncthreads();
  }
  for (int a = 0; a < 4; ++a) {
    int row = bm + tm + a;
    for (int c = 0; c < 4; ++c) {
      int col = bn + tn + c;
      float v = acc[a][c];
      if (bias) v += bias[col];
      if (C0)   v += C0[(size_t)row * ldc + col];
      C[(size_t)row * ldc + col] = v;
    }
  }
}

// ---------------- per-step: GRU combine + cos-gate + BN3 ----------------
__global__ __launch_bounds__(512) void combine(
    const float* __restrict__ gix, const float* __restrict__ ghx,
    const float* __restrict__ ghm, const float* __restrict__ gim_all,
    float* __restrict__ hx, float* __restrict__ hm,
    const float* __restrict__ g3, const float* __restrict__ b3,
    float* __restrict__ out_bn, int step)
{
  int t = threadIdx.x;
  int b = t >> 2, c = t & 3;
  int h = blockIdx.x * 4 + c;
  const float* gi  = gix + (size_t)b * TH_;
  const float* gh  = ghx + (size_t)b * TH_;
  float r  = sigm(gi[h] + gh[h]);
  float zg = sigm(gi[512+h] + gh[512+h]);
  float n  = tanhf(gi[1024+h] + r * gh[1024+h]);
  float hxv = hx[b*H_ + h];
  float hx2 = (1.f - zg) * n + zg * hxv;
  const float* gm  = gim_all + (size_t)step * TH_;
  const float* ghb = ghm + (size_t)b * TH_;
  float rm = sigm(gm[h] + ghb[h]);
  float zm = sigm(gm[512+h] + ghb[512+h]);
  float nm = tanhf(gm[1024+h] + rm * ghb[1024+h]);
  float hmv = hm[b*H_ + h];
  float hm2 = (1.f - zm) * nm + zm * hmv;
  hx[b*H_ + h] = hx2;
  hm[b*H_ + h] = hm2;
  // cosine gate over SIM=4 group (lanes c=0..3 are adjacent)
  float dab = hx2 * hm2, na = hx2 * hx2, nb = hm2 * hm2;
  dab += __shfl_xor(dab, 1); dab += __shfl_xor(dab, 2);
  na  += __shfl_xor(na, 1);  na  += __shfl_xor(na, 2);
  nb  += __shfl_xor(nb, 1);  nb  += __shfl_xor(nb, 2);
  float denom = fmaxf(sqrtf(na) * sqrtf(nb), 1e-8f);
  float gate = dab / denom;
  float out = leaky(gate * hx2 + (1.f - gate) * hm2);
  // BN3 over batch (rows spread across b within block)
  __shared__ float red[512];
  red[t] = out; __syncthreads();
  for (int s = 64; s > 0; s >>= 1) { if (b < s) red[b*4+c] += red[(b+s)*4+c]; __syncthreads(); }
  float mu = red[c] * (1.f/128.f); __syncthreads();
  float d = out - mu;
  red[t] = d * d; __syncthreads();
  for (int s = 64; s > 0; s >>= 1) { if (b < s) red[b*4+c] += red[(b+s)*4+c]; __syncthreads(); }
  float var = red[c] * (1.f/128.f);
  out_bn[b*H_ + h] = (g3[h] * d) * (1.f / sqrtf(var + 1e-5f)) + b3[h];
}

// ---------------- per-step: logits + exact JAX Gumbel, staged into d_out --
__global__ __launch_bounds__(256) void logits_gumbel(
    const float* __restrict__ A,     // out_bn 128x512
    const float* __restrict__ W,     // h2o_w 8192x512
    const float* __restrict__ bias,  // h2o_b
    const float* __restrict__ temp,
    float* __restrict__ outbase,     // d_out
    int step)
{
  __shared__ float As[GBM][GBK+1];
  __shared__ float Bs[GBN][GBK+1];
  int bm = blockIdx.y * GBM, bn = blockIdx.x * GBN;
  int tid = threadIdx.x;
  int tm = (tid >> 4) << 2, tn = (tid & 15) << 2;
  float acc[4][4] = {};
  for (int k0 = 0; k0 < H_; k0 += GBK) {
    for (int i = tid; i < GBM * GBK; i += 256) {
      int r = i >> 5, c = i & 31;
      As[r][c] = A[(size_t)(bm + r) * H_ + k0 + c];
      Bs[r][c] = W[(size_t)(bn + r) * H_ + k0 + c];
    }
    __syncthreads();
    #pragma unroll
    for (int k = 0; k < GBK; ++k) {
      float av[4], bv[4];
      #pragma unroll
      for (int q = 0; q < 4; ++q) { av[q] = As[tm+q][k]; bv[q] = Bs[tn+q][k]; }
      #pragma unroll
      for (int a = 0; a < 4; ++a)
        #pragma unroll
        for (int c = 0; c < 4; ++c)
          acc[a][c] += av[a] * bv[c];
    }
    __syncthreads();
  }
  // fold_in(key(42), step): key_i = threefry((0,42), (0, step))
  unsigned kx = 0u, ky = (unsigned)step;
  threefry(0u, 42u, kx, ky);
  float T = temp[0];
  const float minv = 1e-6f;
  const float maxv = (float)(1.0 - 1e-6);
  const float span = maxv - minv;
  for (int a = 0; a < 4; ++a) {
    int row = bm + tm + a;
    for (int c = 0; c < 4; ++c) {
      int col = bn + tn + c;
      float l = acc[a][c] + bias[col];
      // partitionable threefry bits: out0 ^ out1 of block (hi=0, lo=m)
      unsigned x0 = 0u, x1 = (unsigned)(row * V_ + col);
      threefry(kx, ky, x0, x1);
      unsigned bits = x0 ^ x1;
      float f = __uint_as_float((bits >> 9) | 0x3f800000u) - 1.0f;
      float u = fmaxf(__fadd_rn(__fmul_rn(f, span), minv), minv);
      float g = -logf(-logf(u));
      outbase[(size_t)row * (S_ * V_) + (size_t)step * V_ + col] = (l + g) / T;
    }
  }
}

// ---------------- per-step: row softmax (in place in d_out) + argmax ------
__global__ __launch_bounds__(256) void softmax_fin(
    float* __restrict__ outbase, int step, int* __restrict__ prev)
{
  int b = blockIdx.x, t = threadIdx.x;
  float* row = outbase + (size_t)b * (S_ * V_) + (size_t)step * V_;
  __shared__ float sv[256];
  __shared__ int   si[256];
  float lmax = -3.4e38f; int lidx = 0;
  for (int k = t; k < V_; k += 256) {
    float v = row[k];
    if (v > lmax) { lmax = v; lidx = k; }
  }
  sv[t] = lmax; si[t] = lidx; __syncthreads();
  for (int s = 128; s > 0; s >>= 1) {
    if (t < s) {
      float v2 = sv[t+s]; int i2 = si[t+s];
      if (v2 > sv[t] || (v2 == sv[t] && i2 < si[t])) { sv[t] = v2; si[t] = i2; }
    }
    __syncthreads();
  }
  float rmax = sv[0];
  if (t == 0) prev[b] = si[0];
  __syncthreads();
  float ls = 0.f;
  for (int k = t; k < V_; k += 256) ls += expf(row[k] - rmax);
  sv[t] = ls; __syncthreads();
  for (int s = 128; s > 0; s >>= 1) { if (t < s) sv[t] += sv[t+s]; __syncthreads(); }
  float rsum = sv[0];
  for (int k = t; k < V_; k += 256) row[k] = expf(row[k] - rmax) / rsum;
}

extern "C" void kernel_launch(void* const* d_in, const int* in_sizes, int n_in,
                              void* d_out, int out_size, void* d_ws, size_t ws_size,
                              hipStream_t stream) {
  const float* z      = (const float*)d_in[0];
  const float* temp   = (const float*)d_in[1];
  const float* z2h_w  = (const float*)d_in[2];
  const float* z2h_b  = (const float*)d_in[3];
  const float* bn1_g  = (const float*)d_in[4];
  const float* bn1_b  = (const float*)d_in[5];
  const float* emb    = (const float*)d_in[6];
  const float* bn2_g  = (const float*)d_in[7];
  const float* bn2_b  = (const float*)d_in[8];
  const float* memory = (const float*)d_in[9];
  const float* gx_wih = (const float*)d_in[10];
  const float* gx_whh = (const float*)d_in[11];
  const float* gx_bih = (const float*)d_in[12];
  const float* gx_bhh = (const float*)d_in[13];
  const float* gm_wih = (const float*)d_in[14];
  const float* gm_whh = (const float*)d_in[15];
  const float* gm_bih = (const float*)d_in[16];
  const float* gm_bhh = (const float*)d_in[17];
  const float* bn3_g  = (const float*)d_in[18];
  const float* bn3_b  = (const float*)d_in[19];
  const float* h2o_w  = (const float*)d_in[20];
  const float* h2o_b  = (const float*)d_in[21];
  float* out = (float*)d_out;

  // workspace layout (floats)
  float* w      = (float*)d_ws;
  float* si_z   = w;               // 65536
  float* gi_z   = w + 65536;       // 196608
  float* gim    = w + 262144;      // 98304
  float* x_bn   = w + 360448;      // 65536
  float* hx     = w + 425984;      // 65536
  float* hm     = w + 491520;      // 65536
  float* gix    = w + 557056;      // 196608
  float* ghx    = w + 753664;      // 196608
  float* ghm    = w + 950272;      // 196608
  float* out_bn = w + 1146880;     // 65536
  int*   prev   = (int*)(w + 1212416); // 128 ints

  // setup
  setup_z0<<<512, 128, 0, stream>>>(z, z2h_w, z2h_b, bn1_g, bn1_b, bn2_g, bn2_b,
                                    hx, hm, si_z, prev);
  // gi_z = si_z @ gx_wih[:,512:].T + gx_bih   (step-invariant input-GEMM half)
  gemm_nt<<<dim3(24, 2), 256, 0, stream>>>(si_z, H_, gx_wih + 512, H2_,
                                           gx_bih, nullptr, gi_z, TH_, H_);
  // gim[i] = mem_i @ gm_wih.T + gm_bih  for all 64 steps at once
  gemm_nt<<<dim3(24, 1), 256, 0, stream>>>(memory, H2_, gm_wih, H2_,
                                           gm_bih, nullptr, gim, TH_, H2_);

  for (int i = 0; i < S_; ++i) {
    embed_bn<<<512, 128, 0, stream>>>(emb, prev, bn2_g, bn2_b, x_bn);
    // gix = x_bn @ gx_wih[:,:512].T + gi_z
    gemm_nt<<<dim3(24, 2), 256, 0, stream>>>(x_bn, H_, gx_wih, H2_,
                                             nullptr, gi_z, gix, TH_, H_);
    // ghx = hx @ gx_whh.T + gx_bhh
    gemm_nt<<<dim3(24, 2), 256, 0, stream>>>(hx, H_, gx_whh, H_,
                                             gx_bhh, nullptr, ghx, TH_, H_);
    // ghm = hm @ gm_whh.T + gm_bhh
    gemm_nt<<<dim3(24, 2), 256, 0, stream>>>(hm, H_, gm_whh, H_,
                                             gm_bhh, nullptr, ghm, TH_, H_);
    combine<<<128, 512, 0, stream>>>(gix, ghx, ghm, gim, hx, hm,
                                     bn3_g, bn3_b, out_bn, i);
    logits_gumbel<<<dim3(128, 2), 256, 0, stream>>>(out_bn, h2o_w, h2o_b,
                                                    temp, out, i);
    softmax_fin<<<128, 256, 0, stream>>>(out, i, prev);
  }
}